// Round 1
// baseline (720.517 us; speedup 1.0000x reference)
//
#include <hip/hip_runtime.h>
#include <cstdint>
#include <cstddef>

#define NTOK 4096
#define DMODEL 1024
#define NHEAD 8
#define DHEAD 128
#define DFFN 1536
#define LNEPS 1e-5f

typedef __bf16 bf16_t;
typedef __bf16 bf16x8 __attribute__((ext_vector_type(8)));
typedef __bf16 bf16x4 __attribute__((ext_vector_type(4)));
typedef float f32x4 __attribute__((ext_vector_type(4)));

__device__ __forceinline__ void gload_lds16(const bf16_t* g, bf16_t* lds) {
  __builtin_amdgcn_global_load_lds(
      (const __attribute__((address_space(1))) unsigned int*)g,
      (__attribute__((address_space(3))) unsigned int*)lds, 16, 0, 0);
}

// ---------------- f32 -> bf16 convert ----------------
__global__ __launch_bounds__(256) void cvt_kernel(const float* __restrict__ in,
                                                  bf16_t* __restrict__ out, int n4) {
  int i = blockIdx.x * 256 + threadIdx.x;
  if (i < n4) {
    const float4 v = reinterpret_cast<const float4*>(in)[i];
    bf16x4 o = {(bf16_t)v.x, (bf16_t)v.y, (bf16_t)v.z, (bf16_t)v.w};
    reinterpret_cast<bf16x4*>(out)[i] = o;
  }
}

// ---------------- bf16 GEMM, C = A @ B^T (+ epilogue) ----------------
// A [M,K] row-major bf16, B [N,K] row-major bf16 (torch Linear weight layout).
// EPI 0: outH = bf16(C)
// EPI 1: outF = C + bias[col] + resid
// EPI 2: outH = bf16(gelu_erf(C + bias[col]))
// EPI 3: outF = C + bias[col] + resid
template<int EPI>
__global__ __launch_bounds__(256) void gemm_bt(
    const bf16_t* __restrict__ A, const bf16_t* __restrict__ B,
    int M, int Nn, int K,
    const float* __restrict__ bias, const float* __restrict__ resid,
    float* __restrict__ outF, bf16_t* __restrict__ outH)
{
  __shared__ bf16_t As[128 * 32];
  __shared__ bf16_t Bs[128 * 32];
  const int t = threadIdx.x;
  const int w = t >> 6, l = t & 63;
  const int lg = l >> 4, li = l & 15;
  const int m0 = blockIdx.x * 128, n0 = blockIdx.y * 128;
  const int wr = (w >> 1) * 64, wc = (w & 1) * 64;
  const f32x4 fz = {0.f, 0.f, 0.f, 0.f};
  f32x4 acc[4][4];
#pragma unroll
  for (int i = 0; i < 4; i++)
#pragma unroll
    for (int j = 0; j < 4; j++) acc[i][j] = fz;

  const bf16_t* Ag = A + (size_t)m0 * K;
  const bf16_t* Bg = B + (size_t)n0 * K;

  for (int kt = 0; kt < K; kt += 32) {
    if (kt) __syncthreads();
#pragma unroll
    for (int p = 0; p < 2; p++) {
      int c = p * 256 + w * 64 + l;
      gload_lds16(Ag + (size_t)(c >> 2) * K + kt + (c & 3) * 8,
                  As + (p * 256 + w * 64) * 8);
      gload_lds16(Bg + (size_t)(c >> 2) * K + kt + (c & 3) * 8,
                  Bs + (p * 256 + w * 64) * 8);
    }
    __syncthreads();
    bf16x8 af[4], bfr[4];
#pragma unroll
    for (int mi = 0; mi < 4; mi++)
      af[mi] = *reinterpret_cast<const bf16x8*>(&As[(wr + mi * 16 + li) * 32 + lg * 8]);
#pragma unroll
    for (int ni = 0; ni < 4; ni++)
      bfr[ni] = *reinterpret_cast<const bf16x8*>(&Bs[(wc + ni * 16 + li) * 32 + lg * 8]);
#pragma unroll
    for (int mi = 0; mi < 4; mi++)
#pragma unroll
      for (int ni = 0; ni < 4; ni++)
        acc[mi][ni] = __builtin_amdgcn_mfma_f32_16x16x32_bf16(af[mi], bfr[ni], acc[mi][ni], 0, 0, 0);
  }

#pragma unroll
  for (int mi = 0; mi < 4; mi++) {
#pragma unroll
    for (int ni = 0; ni < 4; ni++) {
      int gcol = n0 + wc + ni * 16 + li;
#pragma unroll
      for (int r = 0; r < 4; r++) {
        int grow = m0 + wr + mi * 16 + lg * 4 + r;
        float v = acc[mi][ni][r];
        if (EPI == 0) {
          outH[(size_t)grow * Nn + gcol] = (bf16_t)v;
        } else if (EPI == 1) {
          v += bias[gcol] + resid[(size_t)grow * Nn + gcol];
          outF[(size_t)grow * Nn + gcol] = v;
        } else if (EPI == 2) {
          v += bias[gcol];
          v = 0.5f * v * (1.f + erff(v * 0.70710678118654752f));
          outH[(size_t)grow * Nn + gcol] = (bf16_t)v;
        } else {
          v += bias[gcol] + resid[(size_t)grow * Nn + gcol];
          outF[(size_t)grow * Nn + gcol] = v;
        }
      }
    }
  }
}

// ---------------- bf16 transpose [NTOK,DMODEL] -> [DMODEL,NTOK] ----------------
__global__ __launch_bounds__(256) void transpose_kernel(const bf16_t* __restrict__ in,
                                                        bf16_t* __restrict__ out)
{
  __shared__ bf16_t tile[64][72];  // 72*2=144B row stride, 16B aligned
  int t = threadIdx.x;
  int nb = blockIdx.x * 64, db = blockIdx.y * 64;
#pragma unroll
  for (int p = 0; p < 2; p++) {
    int c = p * 256 + t;
    int n = c >> 3, cb = c & 7;
    bf16x8 v = *reinterpret_cast<const bf16x8*>(in + (size_t)(nb + n) * DMODEL + db + cb * 8);
    *reinterpret_cast<bf16x8*>(&tile[n][cb * 8]) = v;
  }
  __syncthreads();
#pragma unroll
  for (int p = 0; p < 2; p++) {
    int c = p * 256 + t;
    int d = c >> 3, nc = (c & 7) * 8;
    bf16x8 vv;
#pragma unroll
    for (int j = 0; j < 8; j++) vv[j] = tile[nc + j][d];
    *reinterpret_cast<bf16x8*>(out + (size_t)(db + d) * NTOK + nb + nc) = vv;
  }
}

// ---------------- fused dual-softmax flash attention ----------------
// Q,K: [NTOK, DMODEL] bf16 (head h = cols h*128..+128). Vt: [DMODEL, NTOK] bf16.
// out: [NTOK, DMODEL] bf16 = softmax(S-bias) @ V - 1.5 * softmax((-S-bias)/0.6) @ V
__global__ __launch_bounds__(256) void attn_kernel(
    const bf16_t* __restrict__ Q, const bf16_t* __restrict__ K,
    const bf16_t* __restrict__ Vt, const int* __restrict__ coords,
    bf16_t* __restrict__ out)
{
  __shared__ bf16_t Ks[64 * DHEAD];      // [64 kv][128 d], XOR-swizzled 16B blocks
  __shared__ bf16_t Vts[DHEAD * 64];     // [128 d][64 kv], swizzled
  __shared__ bf16_t Ps[2][4][16 * 64];   // [pos/neg][wave][16 q][64 kv], swizzled

  const int t = threadIdx.x;
  const int w = t >> 6, l = t & 63;
  const int lg = l >> 4, li = l & 15;
  const int h = blockIdx.x & 7;          // same head -> same XCD (round-robin)
  const int q0 = (blockIdx.x >> 3) * 64;
  const float hs = 1.0f / (float)(2 << h);
  const float isq = 0.08838834764831845f;   // 1/sqrt(128)
  const float itau = 1.6666666666666667f;   // 1/0.6

  bf16x8 qf[4];
  {
    const bf16_t* qrow = Q + (size_t)(q0 + w * 16 + li) * DMODEL + h * DHEAD;
#pragma unroll
    for (int ks = 0; ks < 4; ks++)
      qf[ks] = *reinterpret_cast<const bf16x8*>(qrow + ks * 32 + lg * 8);
  }
  float qx[4], qy[4];
#pragma unroll
  for (int r = 0; r < 4; r++) {
    int row = q0 + w * 16 + lg * 4 + r;
    qx[r] = (float)coords[row * 2 + 0];
    qy[r] = (float)coords[row * 2 + 1];
  }

  const f32x4 fz = {0.f, 0.f, 0.f, 0.f};
  f32x4 accp[8], accn[8];
#pragma unroll
  for (int i = 0; i < 8; i++) { accp[i] = fz; accn[i] = fz; }
  float mp[4], lp[4], mn[4], lnn[4];
#pragma unroll
  for (int r = 0; r < 4; r++) { mp[r] = -3e38f; mn[r] = -3e38f; lp[r] = 0.f; lnn[r] = 0.f; }

  for (int kv0 = 0; kv0 < NTOK; kv0 += 64) {
    __syncthreads();
    // stage K tile [64][128] and Vt tile [128][64], both swizzled: block ^= (row&7)
#pragma unroll
    for (int p = 0; p < 4; p++) {
      int c = p * 256 + t;
      int row = c >> 4, cb = c & 15;
      bf16x8 v = *reinterpret_cast<const bf16x8*>(K + (size_t)(kv0 + row) * DMODEL + h * DHEAD + cb * 8);
      *reinterpret_cast<bf16x8*>(&Ks[row * DHEAD + ((cb ^ (row & 7)) << 3)]) = v;
      int d = c >> 3, vb = c & 7;
      bf16x8 v2 = *reinterpret_cast<const bf16x8*>(Vt + (size_t)(h * DHEAD + d) * NTOK + kv0 + vb * 8);
      *reinterpret_cast<bf16x8*>(&Vts[d * 64 + ((vb ^ (d & 7)) << 3)]) = v2;
    }
    __syncthreads();

    // S = Q K^T for this wave's 16x64 strip
    f32x4 sacc[4];
#pragma unroll
    for (int nf = 0; nf < 4; nf++) sacc[nf] = fz;
#pragma unroll
    for (int ks = 0; ks < 4; ks++) {
#pragma unroll
      for (int nf = 0; nf < 4; nf++) {
        int kn = nf * 16 + li;
        int cb = ks * 4 + lg;
        bf16x8 kf = *reinterpret_cast<const bf16x8*>(&Ks[kn * DHEAD + ((cb ^ (kn & 7)) << 3)]);
        sacc[nf] = __builtin_amdgcn_mfma_f32_16x16x32_bf16(qf[ks], kf, sacc[nf], 0, 0, 0);
      }
    }

    // bias + dual online softmax. Lane holds rows lg*4+r, cols li+16*nf.
    float sp[4][4], sn[4][4];
#pragma unroll
    for (int nf = 0; nf < 4; nf++) {
      int ck = kv0 + nf * 16 + li;
      float kx = (float)coords[ck * 2 + 0];
      float ky = (float)coords[ck * 2 + 1];
#pragma unroll
      for (int r = 0; r < 4; r++) {
        float s = sacc[nf][r] * isq;
        float dx = qx[r] - kx, dy = qy[r] - ky;
        float b = sqrtf(dx * dx + dy * dy) * hs;
        sp[nf][r] = s - b;
        sn[nf][r] = -(s + b) * itau;
      }
    }
    float tp[4], tn[4];
#pragma unroll
    for (int r = 0; r < 4; r++) {
      tp[r] = fmaxf(fmaxf(sp[0][r], sp[1][r]), fmaxf(sp[2][r], sp[3][r]));
      tn[r] = fmaxf(fmaxf(sn[0][r], sn[1][r]), fmaxf(sn[2][r], sn[3][r]));
    }
#pragma unroll
    for (int msk = 1; msk < 16; msk <<= 1) {
#pragma unroll
      for (int r = 0; r < 4; r++) {
        tp[r] = fmaxf(tp[r], __shfl_xor(tp[r], msk, 64));
        tn[r] = fmaxf(tn[r], __shfl_xor(tn[r], msk, 64));
      }
    }
    float cp[4], cn[4];
#pragma unroll
    for (int r = 0; r < 4; r++) {
      float mpn = fmaxf(mp[r], tp[r]);
      cp[r] = __expf(mp[r] - mpn); mp[r] = mpn;
      float mnn = fmaxf(mn[r], tn[r]);
      cn[r] = __expf(mn[r] - mnn); cn[r] = cn[r]; mn[r] = mnn;
    }
    float rp[4] = {0.f, 0.f, 0.f, 0.f}, rn[4] = {0.f, 0.f, 0.f, 0.f};
#pragma unroll
    for (int nf = 0; nf < 4; nf++)
#pragma unroll
      for (int r = 0; r < 4; r++) {
        float pv = __expf(sp[nf][r] - mp[r]); sp[nf][r] = pv; rp[r] += pv;
        float nv = __expf(sn[nf][r] - mn[r]); sn[nf][r] = nv; rn[r] += nv;
      }
#pragma unroll
    for (int msk = 1; msk < 16; msk <<= 1)
#pragma unroll
      for (int r = 0; r < 4; r++) {
        rp[r] += __shfl_xor(rp[r], msk, 64);
        rn[r] += __shfl_xor(rn[r], msk, 64);
      }
#pragma unroll
    for (int r = 0; r < 4; r++) {
      lp[r] = lp[r] * cp[r] + rp[r];
      lnn[r] = lnn[r] * cn[r] + rn[r];
    }
    // write P tiles (C-layout -> swizzled LDS)
#pragma unroll
    for (int nf = 0; nf < 4; nf++)
#pragma unroll
      for (int r = 0; r < 4; r++) {
        int rl = lg * 4 + r;
        int col = nf * 16 + li;
        int e = rl * 64 + ((((col >> 3) ^ (rl & 7))) << 3) + (col & 7);
        Ps[0][w][e] = (bf16_t)sp[nf][r];
        Ps[1][w][e] = (bf16_t)sn[nf][r];
      }
    // rescale accumulators
#pragma unroll
    for (int nf = 0; nf < 8; nf++)
#pragma unroll
      for (int r = 0; r < 4; r++) {
        accp[nf][r] *= cp[r];
        accn[nf][r] *= cn[r];
      }
    __syncthreads();
    // PV: A-frags from Ps (wave-private strip), B-frags from Vts
#pragma unroll
    for (int ks = 0; ks < 2; ks++) {
      int cb = ks * 4 + lg;
      bf16x8 pa = *reinterpret_cast<const bf16x8*>(&Ps[0][w][li * 64 + ((cb ^ (li & 7)) << 3)]);
      bf16x8 na = *reinterpret_cast<const bf16x8*>(&Ps[1][w][li * 64 + ((cb ^ (li & 7)) << 3)]);
#pragma unroll
      for (int nf = 0; nf < 8; nf++) {
        int vd = nf * 16 + li;
        bf16x8 vbf = *reinterpret_cast<const bf16x8*>(&Vts[vd * 64 + ((cb ^ (vd & 7)) << 3)]);
        accp[nf] = __builtin_amdgcn_mfma_f32_16x16x32_bf16(pa, vbf, accp[nf], 0, 0, 0);
        accn[nf] = __builtin_amdgcn_mfma_f32_16x16x32_bf16(na, vbf, accn[nf], 0, 0, 0);
      }
    }
  }

  float ip[4], inn[4];
#pragma unroll
  for (int r = 0; r < 4; r++) { ip[r] = 1.f / lp[r]; inn[r] = 1.5f / lnn[r]; }
#pragma unroll
  for (int nf = 0; nf < 8; nf++) {
    int gcol = h * DHEAD + nf * 16 + li;
#pragma unroll
    for (int r = 0; r < 4; r++) {
      int grow = q0 + w * 16 + lg * 4 + r;
      float v = accp[nf][r] * ip[r] - accn[nf][r] * inn[r];
      out[(size_t)grow * DMODEL + gcol] = (bf16_t)v;
    }
  }
}

// ---------------- row LayerNorm (D=1024), optional f32 + bf16 outputs ----------------
__global__ __launch_bounds__(256) void ln_kernel(
    const float* __restrict__ in, const float* __restrict__ g, const float* __restrict__ b,
    float* __restrict__ outF, bf16_t* __restrict__ outH)
{
  int row = blockIdx.x, t = threadIdx.x;
  const float4 v = reinterpret_cast<const float4*>(in + (size_t)row * DMODEL)[t];
  float s = v.x + v.y + v.z + v.w;
  float ss = v.x * v.x + v.y * v.y + v.z * v.z + v.w * v.w;
#pragma unroll
  for (int m = 32; m >= 1; m >>= 1) {
    s += __shfl_xor(s, m, 64);
    ss += __shfl_xor(ss, m, 64);
  }
  __shared__ float red[8];
  int w = t >> 6, l = t & 63;
  if (l == 0) { red[w] = s; red[4 + w] = ss; }
  __syncthreads();
  s = red[0] + red[1] + red[2] + red[3];
  ss = red[4] + red[5] + red[6] + red[7];
  float mu = s * (1.f / DMODEL);
  float var = ss * (1.f / DMODEL) - mu * mu;
  float rs = rsqrtf(var + LNEPS);
  const float4 gv = reinterpret_cast<const float4*>(g)[t];
  const float4 bv = reinterpret_cast<const float4*>(b)[t];
  float y0 = (v.x - mu) * rs * gv.x + bv.x;
  float y1 = (v.y - mu) * rs * gv.y + bv.y;
  float y2 = (v.z - mu) * rs * gv.z + bv.z;
  float y3 = (v.w - mu) * rs * gv.w + bv.w;
  if (outF) {
    float4 o; o.x = y0; o.y = y1; o.z = y2; o.w = y3;
    reinterpret_cast<float4*>(outF + (size_t)row * DMODEL)[t] = o;
  }
  if (outH) {
    bf16x4 o = {(bf16_t)y0, (bf16_t)y1, (bf16_t)y2, (bf16_t)y3};
    reinterpret_cast<bf16x4*>(outH + (size_t)row * DMODEL)[t] = o;
  }
}

extern "C" void kernel_launch(void* const* d_in, const int* in_sizes, int n_in,
                              void* d_out, int out_size, void* d_ws, size_t ws_size,
                              hipStream_t stream) {
  (void)in_sizes; (void)n_in; (void)out_size; (void)ws_size;
  const float* features = (const float*)d_in[0];
  const int* coords = (const int*)d_in[1];
  const float* Wq = (const float*)d_in[2];
  const float* Wk = (const float*)d_in[3];
  const float* Wv = (const float*)d_in[4];
  const float* Wo = (const float*)d_in[5];
  const float* bo = (const float*)d_in[6];
  const float* ln1g = (const float*)d_in[7];
  const float* ln1b = (const float*)d_in[8];
  const float* W1 = (const float*)d_in[9];
  const float* b1 = (const float*)d_in[10];
  const float* W2 = (const float*)d_in[11];
  const float* b2 = (const float*)d_in[12];
  const float* ln2g = (const float*)d_in[13];
  const float* ln2b = (const float*)d_in[14];
  float* outp = (float*)d_out;

  char* ws = (char*)d_ws;
  size_t off = 0;
  auto alloc = [&](size_t bytes) -> void* {
    void* p = ws + off;
    off += (bytes + 255) & ~((size_t)255);
    return p;
  };
  bf16_t* fb16 = (bf16_t*)alloc((size_t)NTOK * DMODEL * 2);   // also reused as att16
  bf16_t* wq16 = (bf16_t*)alloc((size_t)DMODEL * DMODEL * 2);
  bf16_t* wk16 = (bf16_t*)alloc((size_t)DMODEL * DMODEL * 2);
  bf16_t* wv16 = (bf16_t*)alloc((size_t)DMODEL * DMODEL * 2);
  bf16_t* wo16 = (bf16_t*)alloc((size_t)DMODEL * DMODEL * 2);
  bf16_t* w116 = (bf16_t*)alloc((size_t)DFFN * DMODEL * 2);
  bf16_t* w216 = (bf16_t*)alloc((size_t)DMODEL * DFFN * 2);
  bf16_t* q16 = (bf16_t*)alloc((size_t)NTOK * DMODEL * 2);
  bf16_t* k16 = (bf16_t*)alloc((size_t)NTOK * DMODEL * 2);
  bf16_t* v16 = (bf16_t*)alloc((size_t)NTOK * DMODEL * 2);
  bf16_t* vt16 = (bf16_t*)alloc((size_t)NTOK * DMODEL * 2);
  float* acc1 = (float*)alloc((size_t)NTOK * DMODEL * 4);     // wo_out / ffn_out
  float* xf = (float*)alloc((size_t)NTOK * DMODEL * 4);
  bf16_t* x16 = (bf16_t*)alloc((size_t)NTOK * DMODEL * 2);
  bf16_t* h16 = (bf16_t*)alloc((size_t)NTOK * DFFN * 2);
  bf16_t* att16 = fb16;

  cvt_kernel<<<dim3(NTOK * DMODEL / 1024), 256, 0, stream>>>(features, fb16, NTOK * DMODEL / 4);
  cvt_kernel<<<dim3(DMODEL * DMODEL / 1024), 256, 0, stream>>>(Wq, wq16, DMODEL * DMODEL / 4);
  cvt_kernel<<<dim3(DMODEL * DMODEL / 1024), 256, 0, stream>>>(Wk, wk16, DMODEL * DMODEL / 4);
  cvt_kernel<<<dim3(DMODEL * DMODEL / 1024), 256, 0, stream>>>(Wv, wv16, DMODEL * DMODEL / 4);
  cvt_kernel<<<dim3(DMODEL * DMODEL / 1024), 256, 0, stream>>>(Wo, wo16, DMODEL * DMODEL / 4);
  cvt_kernel<<<dim3(DFFN * DMODEL / 1024), 256, 0, stream>>>(W1, w116, DFFN * DMODEL / 4);
  cvt_kernel<<<dim3(DMODEL * DFFN / 1024), 256, 0, stream>>>(W2, w216, DMODEL * DFFN / 4);

  dim3 gQKV(NTOK / 128, DMODEL / 128);
  gemm_bt<0><<<gQKV, 256, 0, stream>>>(fb16, wq16, NTOK, DMODEL, DMODEL, nullptr, nullptr, nullptr, q16);
  gemm_bt<0><<<gQKV, 256, 0, stream>>>(fb16, wk16, NTOK, DMODEL, DMODEL, nullptr, nullptr, nullptr, k16);
  gemm_bt<0><<<gQKV, 256, 0, stream>>>(fb16, wv16, NTOK, DMODEL, DMODEL, nullptr, nullptr, nullptr, v16);
  transpose_kernel<<<dim3(NTOK / 64, DMODEL / 64), 256, 0, stream>>>(v16, vt16);
  attn_kernel<<<dim3(NTOK / 64 * NHEAD), 256, 0, stream>>>(q16, k16, vt16, coords, att16);
  gemm_bt<1><<<gQKV, 256, 0, stream>>>(att16, wo16, NTOK, DMODEL, DMODEL, bo, features, acc1, nullptr);
  ln_kernel<<<dim3(NTOK), 256, 0, stream>>>(acc1, ln1g, ln1b, xf, x16);
  gemm_bt<2><<<dim3(NTOK / 128, DFFN / 128), 256, 0, stream>>>(x16, w116, NTOK, DFFN, DMODEL, b1, nullptr, nullptr, h16);
  gemm_bt<3><<<gQKV, 256, 0, stream>>>(h16, w216, NTOK, DMODEL, DFFN, b2, xf, acc1, nullptr);
  ln_kernel<<<dim3(NTOK), 256, 0, stream>>>(acc1, ln2g, ln2b, outp, nullptr);
}

// Round 3
// 620.247 us; speedup vs baseline: 1.1617x; 1.1617x over previous
//
#include <hip/hip_runtime.h>
#include <cstdint>
#include <cstddef>

#define NTOK 4096
#define DMODEL 1024
#define NHEAD 8
#define DHEAD 128
#define DFFN 1536
#define LNEPS 1e-5f

typedef __bf16 bf16_t;
typedef __bf16 bf16x8 __attribute__((ext_vector_type(8)));
typedef __bf16 bf16x4 __attribute__((ext_vector_type(4)));
typedef float f32x4 __attribute__((ext_vector_type(4)));
typedef float f32x16 __attribute__((ext_vector_type(16)));

__device__ __forceinline__ void gload_lds16(const bf16_t* g, bf16_t* lds) {
  __builtin_amdgcn_global_load_lds(
      (const __attribute__((address_space(1))) unsigned int*)g,
      (__attribute__((address_space(3))) unsigned int*)lds, 16, 0, 0);
}

__device__ __forceinline__ unsigned pkbf(float lo, float hi) {
  unsigned a = (unsigned)__builtin_bit_cast(unsigned short, (bf16_t)lo);
  unsigned b = (unsigned)__builtin_bit_cast(unsigned short, (bf16_t)hi);
  return (b << 16) | a;
}

// ---------------- f32 -> bf16 convert ----------------
__global__ __launch_bounds__(256) void cvt_kernel(const float* __restrict__ in,
                                                  bf16_t* __restrict__ out, int n4) {
  int i = blockIdx.x * 256 + threadIdx.x;
  if (i < n4) {
    const float4 v = reinterpret_cast<const float4*>(in)[i];
    bf16x4 o = {(bf16_t)v.x, (bf16_t)v.y, (bf16_t)v.z, (bf16_t)v.w};
    reinterpret_cast<bf16x4*>(out)[i] = o;
  }
}

// ---------------- bf16 GEMM, C = A @ B^T (+ epilogue) ----------------
template<int EPI>
__global__ __launch_bounds__(256) void gemm_bt(
    const bf16_t* __restrict__ A, const bf16_t* __restrict__ B,
    int M, int Nn, int K,
    const float* __restrict__ bias, const float* __restrict__ resid,
    float* __restrict__ outF, bf16_t* __restrict__ outH)
{
  __shared__ bf16_t As[128 * 32];
  __shared__ bf16_t Bs[128 * 32];
  const int t = threadIdx.x;
  const int w = t >> 6, l = t & 63;
  const int lg = l >> 4, li = l & 15;
  const int m0 = blockIdx.x * 128, n0 = blockIdx.y * 128;
  const int wr = (w >> 1) * 64, wc = (w & 1) * 64;
  const f32x4 fz = {0.f, 0.f, 0.f, 0.f};
  f32x4 acc[4][4];
#pragma unroll
  for (int i = 0; i < 4; i++)
#pragma unroll
    for (int j = 0; j < 4; j++) acc[i][j] = fz;

  const bf16_t* Ag = A + (size_t)m0 * K;
  const bf16_t* Bg = B + (size_t)n0 * K;

  for (int kt = 0; kt < K; kt += 32) {
    if (kt) __syncthreads();
#pragma unroll
    for (int p = 0; p < 2; p++) {
      int c = p * 256 + w * 64 + l;
      gload_lds16(Ag + (size_t)(c >> 2) * K + kt + (c & 3) * 8,
                  As + (p * 256 + w * 64) * 8);
      gload_lds16(Bg + (size_t)(c >> 2) * K + kt + (c & 3) * 8,
                  Bs + (p * 256 + w * 64) * 8);
    }
    __syncthreads();
    bf16x8 af[4], bfr[4];
#pragma unroll
    for (int mi = 0; mi < 4; mi++)
      af[mi] = *reinterpret_cast<const bf16x8*>(&As[(wr + mi * 16 + li) * 32 + lg * 8]);
#pragma unroll
    for (int ni = 0; ni < 4; ni++)
      bfr[ni] = *reinterpret_cast<const bf16x8*>(&Bs[(wc + ni * 16 + li) * 32 + lg * 8]);
#pragma unroll
    for (int mi = 0; mi < 4; mi++)
#pragma unroll
      for (int ni = 0; ni < 4; ni++)
        acc[mi][ni] = __builtin_amdgcn_mfma_f32_16x16x32_bf16(af[mi], bfr[ni], acc[mi][ni], 0, 0, 0);
  }

#pragma unroll
  for (int mi = 0; mi < 4; mi++) {
#pragma unroll
    for (int ni = 0; ni < 4; ni++) {
      int gcol = n0 + wc + ni * 16 + li;
#pragma unroll
      for (int r = 0; r < 4; r++) {
        int grow = m0 + wr + mi * 16 + lg * 4 + r;
        float v = acc[mi][ni][r];
        if (EPI == 0) {
          outH[(size_t)grow * Nn + gcol] = (bf16_t)v;
        } else if (EPI == 1) {
          v += bias[gcol] + resid[(size_t)grow * Nn + gcol];
          outF[(size_t)grow * Nn + gcol] = v;
        } else if (EPI == 2) {
          v += bias[gcol];
          v = 0.5f * v * (1.f + erff(v * 0.70710678118654752f));
          outH[(size_t)grow * Nn + gcol] = (bf16_t)v;
        } else {
          v += bias[gcol] + resid[(size_t)grow * Nn + gcol];
          outF[(size_t)grow * Nn + gcol] = v;
        }
      }
    }
  }
}

// ---------------- bf16 transpose [NTOK,DMODEL] -> [DMODEL,NTOK] ----------------
__global__ __launch_bounds__(256) void transpose_kernel(const bf16_t* __restrict__ in,
                                                        bf16_t* __restrict__ out)
{
  __shared__ bf16_t tile[64][72];
  int t = threadIdx.x;
  int nb = blockIdx.x * 64, db = blockIdx.y * 64;
#pragma unroll
  for (int p = 0; p < 2; p++) {
    int c = p * 256 + t;
    int n = c >> 3, cb = c & 7;
    bf16x8 v = *reinterpret_cast<const bf16x8*>(in + (size_t)(nb + n) * DMODEL + db + cb * 8);
    *reinterpret_cast<bf16x8*>(&tile[n][cb * 8]) = v;
  }
  __syncthreads();
#pragma unroll
  for (int p = 0; p < 2; p++) {
    int c = p * 256 + t;
    int d = c >> 3, nc = (c & 7) * 8;
    bf16x8 vv;
#pragma unroll
    for (int j = 0; j < 8; j++) vv[j] = tile[nc + j][d];
    *reinterpret_cast<bf16x8*>(out + (size_t)(db + d) * NTOK + nb + nc) = vv;
  }
}

// ---------------- fused dual-softmax flash attention, v2 ----------------
// 128 threads = 2 waves. Block covers 32 q-rows of one head; wave w owns
// kv-half w (2048 kv, 64 iters of KVBLK=32). Wave-private LDS staging, no
// main-loop barriers. Swapped QK^T (S^T, q=lane&31), in-register dual
// softmax, shfl_xor(32) P->B-frag redistribution, PV as O^T = V^T * P^T.
__global__ __launch_bounds__(128, 2) void attn2_kernel(
    const bf16_t* __restrict__ Q, const bf16_t* __restrict__ K,
    const bf16_t* __restrict__ Vt, const int* __restrict__ coords,
    bf16_t* __restrict__ out)
{
  // per-wave: Ks 4096 elems (32x128, swizzled) + Vts 5120 elems (128 rows x 40 pitch)
  __shared__ bf16_t lds[2 * 9216];
  __shared__ float mlS[4][32];

  const int t = threadIdx.x;
  const int w = t >> 6;
  const int l = t & 63;
  const int q5 = l & 31;
  const int hi = l >> 5;
  const int h = blockIdx.x & 7;
  const int q0 = (blockIdx.x >> 3) * 32;
  const float hs = 1.0f / (float)(2 << h);
  const float isq = 0.08838834764831845f;   // 1/sqrt(128)
  const float itau = 1.6666666666666667f;   // 1/0.6

  bf16_t* Ks = lds + w * 9216;
  bf16_t* Vts = Ks + 4096;

  // preload Q fragments (B-operand: col q = lane&31, k = d = 16c + 8hi + j)
  bf16x8 qf[8];
  {
    const bf16_t* qrow = Q + (size_t)(q0 + q5) * DMODEL + h * DHEAD;
#pragma unroll
    for (int c = 0; c < 8; c++)
      qf[c] = *reinterpret_cast<const bf16x8*>(qrow + c * 16 + hi * 8);
  }
  const float qx = (float)coords[(q0 + q5) * 2];
  const float qy = (float)coords[(q0 + q5) * 2 + 1];

  f32x16 accp[4], accn[4];
#pragma unroll
  for (int f = 0; f < 4; f++) {
#pragma unroll
    for (int r = 0; r < 16; r++) { accp[f][r] = 0.f; accn[f][r] = 0.f; }
  }
  float mp = -3e38f, mn = -3e38f, lp = 0.f, lN = 0.f;

  const int kvbase = w * 2048;
  for (int it = 0; it < 64; it++) {
    const int kv0 = kvbase + it * 32;

    // ---- wave-private staging (no barriers) ----
    {
      const int row = l >> 1, hf = l & 1;
      const bf16_t* ksrc = K + (size_t)(kv0 + row) * DMODEL + h * DHEAD + hf * 64;
      bf16x8 kreg[8];
#pragma unroll
      for (int j = 0; j < 8; j++) kreg[j] = *reinterpret_cast<const bf16x8*>(ksrc + j * 8);
      const bf16_t* vsrc0 = Vt + (size_t)(h * DHEAD + l) * NTOK + kv0;
      const bf16_t* vsrc1 = vsrc0 + (size_t)64 * NTOK;
      bf16x8 vreg0[4], vreg1[4];
#pragma unroll
      for (int j = 0; j < 4; j++) {
        vreg0[j] = *reinterpret_cast<const bf16x8*>(vsrc0 + j * 8);
        vreg1[j] = *reinterpret_cast<const bf16x8*>(vsrc1 + j * 8);
      }
#pragma unroll
      for (int j = 0; j < 8; j++)
        *reinterpret_cast<bf16x8*>(Ks + row * 128 + (((8 * hf + j) ^ (row & 7)) << 3)) = kreg[j];
      const int vs = (l >> 3) & 3;  // same for d=l and d=l+64
#pragma unroll
      for (int j = 0; j < 4; j++) {
        *reinterpret_cast<bf16x8*>(Vts + l * 40 + ((j ^ vs) << 3)) = vreg0[j];
        *reinterpret_cast<bf16x8*>(Vts + (l + 64) * 40 + ((j ^ vs) << 3)) = vreg1[j];
      }
    }

    // ---- S^T = K * Q^T (32 kv x 32 q), A = K-frag, B = Q-frag ----
    f32x16 sacc;
#pragma unroll
    for (int r = 0; r < 16; r++) sacc[r] = 0.f;
#pragma unroll
    for (int c = 0; c < 8; c++) {
      bf16x8 kf = *reinterpret_cast<const bf16x8*>(
          Ks + q5 * 128 + ((((2 * c + hi)) ^ (q5 & 7)) << 3));
      sacc = __builtin_amdgcn_mfma_f32_32x32x16_bf16(kf, qf[c], sacc, 0, 0, 0);
    }

    // ---- bias + dual online softmax (per lane: one q col, 16 kv rows) ----
    float p16[16], n16[16];
    float tp = -3e38f, tn = -3e38f;
#pragma unroll
    for (int r = 0; r < 16; r++) {
      int kvr = kv0 + (r & 3) + 8 * (r >> 2) + 4 * hi;
      float kx = (float)coords[kvr * 2];
      float ky = (float)coords[kvr * 2 + 1];
      float dx = qx - kx, dy = qy - ky;
      float b = sqrtf(dx * dx + dy * dy) * hs;
      float s = sacc[r] * isq;
      float e1 = s - b;
      float e2 = -(s + b) * itau;
      p16[r] = e1; n16[r] = e2;
      tp = fmaxf(tp, e1); tn = fmaxf(tn, e2);
    }
    tp = fmaxf(tp, __shfl_xor(tp, 32, 64));
    tn = fmaxf(tn, __shfl_xor(tn, 32, 64));

    if (__any((tp > mp + 8.f) || (tn > mn + 8.f))) {
      float mpn = fmaxf(mp, tp), mnn = fmaxf(mn, tn);
      float cp = __expf(mp - mpn), cn = __expf(mn - mnn);
      mp = mpn; mn = mnn; lp *= cp; lN *= cn;
#pragma unroll
      for (int f = 0; f < 4; f++) {
#pragma unroll
        for (int r = 0; r < 16; r++) { accp[f][r] *= cp; accn[f][r] *= cn; }
      }
    }
    float rp = 0.f, rn = 0.f;
#pragma unroll
    for (int r = 0; r < 16; r++) {
      p16[r] = __expf(p16[r] - mp); rp += p16[r];
      n16[r] = __expf(n16[r] - mn); rn += n16[r];
    }
    rp += __shfl_xor(rp, 32, 64);
    rn += __shfl_xor(rn, 32, 64);
    lp += rp; lN += rn;

    // ---- pack P^T to bf16 B-frags, redistribute via shfl_xor(32) ----
    // target word w' on lane half hi_t: pk(kloc_{8*hi_t+2w'}, ..+1),
    // kloc(v,hv) = (v&3)+8*(v>>2)+4*hv.  word0=hi?Bx:A  word2=hi?B:Ax.
    unsigned pw[2][4], nw[2][4];
#pragma unroll
    for (int ks = 0; ks < 2; ks++) {
#pragma unroll
      for (int u = 0; u < 2; u++) {
        unsigned A = pkbf(p16[8 * ks + 2 * u], p16[8 * ks + 2 * u + 1]);
        unsigned B = pkbf(p16[8 * ks + 4 + 2 * u], p16[8 * ks + 4 + 2 * u + 1]);
        unsigned Ax = __shfl_xor(A, 32, 64);
        unsigned Bx = __shfl_xor(B, 32, 64);
        pw[ks][u] = hi ? Bx : A;
        pw[ks][2 + u] = hi ? B : Ax;
        unsigned C = pkbf(n16[8 * ks + 2 * u], n16[8 * ks + 2 * u + 1]);
        unsigned D = pkbf(n16[8 * ks + 4 + 2 * u], n16[8 * ks + 4 + 2 * u + 1]);
        unsigned Cx = __shfl_xor(C, 32, 64);
        unsigned Dx = __shfl_xor(D, 32, 64);
        nw[ks][u] = hi ? Dx : C;
        nw[ks][2 + u] = hi ? D : Cx;
      }
    }

    // ---- PV: O^T += V^T * P^T (A = Vt frags from LDS, B = P words) ----
#pragma unroll
    for (int ks = 0; ks < 2; ks++) {
      union { unsigned u[4]; bf16x8 v; } pb, nb;
#pragma unroll
      for (int j = 0; j < 4; j++) { pb.u[j] = pw[ks][j]; nb.u[j] = nw[ks][j]; }
#pragma unroll
      for (int f = 0; f < 4; f++) {
        int d = 32 * f + q5;
        bf16x8 vf = *reinterpret_cast<const bf16x8*>(
            Vts + d * 40 + (((2 * ks + hi) ^ ((d >> 3) & 3)) << 3));
        accp[f] = __builtin_amdgcn_mfma_f32_32x32x16_bf16(vf, pb.v, accp[f], 0, 0, 0);
        accn[f] = __builtin_amdgcn_mfma_f32_32x32x16_bf16(vf, nb.v, accn[f], 0, 0, 0);
      }
    }
  }

  // ---- cross-wave combine (kv half 0 + half 1) ----
  float* cmbA = reinterpret_cast<float*>(lds);           // [128][32] f32 (16KB)
  float* oT = reinterpret_cast<float*>(lds + 9216);      // [128][33] f32 (16.9KB)

  __syncthreads();
  if (w == 1) {
    if (hi == 0) { mlS[0][q5] = mp; mlS[1][q5] = lp; mlS[2][q5] = mn; mlS[3][q5] = lN; }
#pragma unroll
    for (int f = 0; f < 4; f++)
#pragma unroll
      for (int r = 0; r < 16; r++)
        cmbA[(32 * f + (r & 3) + 8 * (r >> 2) + 4 * hi) * 32 + q5] = accp[f][r];
  }
  __syncthreads();
  float mp1 = mlS[0][q5], lp1 = mlS[1][q5], mn1 = mlS[2][q5], ln1 = mlS[3][q5];
  if (w == 0) {
    float mpc = fmaxf(mp, mp1);
    float e0 = __expf(mp - mpc), e1 = __expf(mp1 - mpc);
    lp = lp * e0 + lp1 * e1;
#pragma unroll
    for (int f = 0; f < 4; f++)
#pragma unroll
      for (int r = 0; r < 16; r++)
        accp[f][r] = accp[f][r] * e0 +
                     cmbA[(32 * f + (r & 3) + 8 * (r >> 2) + 4 * hi) * 32 + q5] * e1;
  }
  __syncthreads();
  if (w == 1) {
#pragma unroll
    for (int f = 0; f < 4; f++)
#pragma unroll
      for (int r = 0; r < 16; r++)
        cmbA[(32 * f + (r & 3) + 8 * (r >> 2) + 4 * hi) * 32 + q5] = accn[f][r];
  }
  __syncthreads();
  if (w == 0) {
    float mnc = fmaxf(mn, mn1);
    float e0 = __expf(mn - mnc), e1 = __expf(mn1 - mnc);
    lN = lN * e0 + ln1 * e1;
    float ip = 1.f / lp, inn = 1.5f / lN;
#pragma unroll
    for (int f = 0; f < 4; f++)
#pragma unroll
      for (int r = 0; r < 16; r++) {
        float an = accn[f][r] * e0 +
                   cmbA[(32 * f + (r & 3) + 8 * (r >> 2) + 4 * hi) * 32 + q5] * e1;
        oT[(32 * f + (r & 3) + 8 * (r >> 2) + 4 * hi) * 33 + q5] =
            accp[f][r] * ip - an * inn;
      }
  }
  __syncthreads();

  // ---- transpose store: thread t -> q = t>>2, d-quarter = (t&3)*32 ----
  {
    int q = t >> 2, dq = (t & 3) * 32;
#pragma unroll
    for (int j = 0; j < 4; j++) {
      bf16x8 ov;
#pragma unroll
      for (int e = 0; e < 8; e++) ov[e] = (bf16_t)oT[(dq + j * 8 + e) * 33 + q];
      *reinterpret_cast<bf16x8*>(out + (size_t)(q0 + q) * DMODEL + h * DHEAD + dq + j * 8) = ov;
    }
  }
}

// ---------------- row LayerNorm (D=1024) ----------------
__global__ __launch_bounds__(256) void ln_kernel(
    const float* __restrict__ in, const float* __restrict__ g, const float* __restrict__ b,
    float* __restrict__ outF, bf16_t* __restrict__ outH)
{
  int row = blockIdx.x, t = threadIdx.x;
  const float4 v = reinterpret_cast<const float4*>(in + (size_t)row * DMODEL)[t];
  float s = v.x + v.y + v.z + v.w;
  float ss = v.x * v.x + v.y * v.y + v.z * v.z + v.w * v.w;
#pragma unroll
  for (int m = 32; m >= 1; m >>= 1) {
    s += __shfl_xor(s, m, 64);
    ss += __shfl_xor(ss, m, 64);
  }
  __shared__ float red[8];
  int w = t >> 6, l = t & 63;
  if (l == 0) { red[w] = s; red[4 + w] = ss; }
  __syncthreads();
  s = red[0] + red[1] + red[2] + red[3];
  ss = red[4] + red[5] + red[6] + red[7];
  float mu = s * (1.f / DMODEL);
  float var = ss * (1.f / DMODEL) - mu * mu;
  float rs = rsqrtf(var + LNEPS);
  const float4 gv = reinterpret_cast<const float4*>(g)[t];
  const float4 bv = reinterpret_cast<const float4*>(b)[t];
  float y0 = (v.x - mu) * rs * gv.x + bv.x;
  float y1 = (v.y - mu) * rs * gv.y + bv.y;
  float y2 = (v.z - mu) * rs * gv.z + bv.z;
  float y3 = (v.w - mu) * rs * gv.w + bv.w;
  if (outF) {
    float4 o; o.x = y0; o.y = y1; o.z = y2; o.w = y3;
    reinterpret_cast<float4*>(outF + (size_t)row * DMODEL)[t] = o;
  }
  if (outH) {
    bf16x4 o = {(bf16_t)y0, (bf16_t)y1, (bf16_t)y2, (bf16_t)y3};
    reinterpret_cast<bf16x4*>(outH + (size_t)row * DMODEL)[t] = o;
  }
}

extern "C" void kernel_launch(void* const* d_in, const int* in_sizes, int n_in,
                              void* d_out, int out_size, void* d_ws, size_t ws_size,
                              hipStream_t stream) {
  (void)in_sizes; (void)n_in; (void)out_size; (void)ws_size;
  const float* features = (const float*)d_in[0];
  const int* coords = (const int*)d_in[1];
  const float* Wq = (const float*)d_in[2];
  const float* Wk = (const float*)d_in[3];
  const float* Wv = (const float*)d_in[4];
  const float* Wo = (const float*)d_in[5];
  const float* bo = (const float*)d_in[6];
  const float* ln1g = (const float*)d_in[7];
  const float* ln1b = (const float*)d_in[8];
  const float* W1 = (const float*)d_in[9];
  const float* b1 = (const float*)d_in[10];
  const float* W2 = (const float*)d_in[11];
  const float* b2 = (const float*)d_in[12];
  const float* ln2g = (const float*)d_in[13];
  const float* ln2b = (const float*)d_in[14];
  float* outp = (float*)d_out;

  char* ws = (char*)d_ws;
  size_t off = 0;
  auto alloc = [&](size_t bytes) -> void* {
    void* p = ws + off;
    off += (bytes + 255) & ~((size_t)255);
    return p;
  };
  bf16_t* fb16 = (bf16_t*)alloc((size_t)NTOK * DMODEL * 2);
  bf16_t* wq16 = (bf16_t*)alloc((size_t)DMODEL * DMODEL * 2);
  bf16_t* wk16 = (bf16_t*)alloc((size_t)DMODEL * DMODEL * 2);
  bf16_t* wv16 = (bf16_t*)alloc((size_t)DMODEL * DMODEL * 2);
  bf16_t* wo16 = (bf16_t*)alloc((size_t)DMODEL * DMODEL * 2);
  bf16_t* w116 = (bf16_t*)alloc((size_t)DFFN * DMODEL * 2);
  bf16_t* w216 = (bf16_t*)alloc((size_t)DMODEL * DFFN * 2);
  bf16_t* q16 = (bf16_t*)alloc((size_t)NTOK * DMODEL * 2);
  bf16_t* k16 = (bf16_t*)alloc((size_t)NTOK * DMODEL * 2);
  bf16_t* v16 = (bf16_t*)alloc((size_t)NTOK * DMODEL * 2);
  bf16_t* vt16 = (bf16_t*)alloc((size_t)NTOK * DMODEL * 2);
  float* acc1 = (float*)alloc((size_t)NTOK * DMODEL * 4);
  float* xf = (float*)alloc((size_t)NTOK * DMODEL * 4);
  bf16_t* x16 = (bf16_t*)alloc((size_t)NTOK * DMODEL * 2);
  bf16_t* h16 = (bf16_t*)alloc((size_t)NTOK * DFFN * 2);
  bf16_t* att16 = fb16;

  cvt_kernel<<<dim3(NTOK * DMODEL / 1024), 256, 0, stream>>>(features, fb16, NTOK * DMODEL / 4);
  cvt_kernel<<<dim3(DMODEL * DMODEL / 1024), 256, 0, stream>>>(Wq, wq16, DMODEL * DMODEL / 4);
  cvt_kernel<<<dim3(DMODEL * DMODEL / 1024), 256, 0, stream>>>(Wk, wk16, DMODEL * DMODEL / 4);
  cvt_kernel<<<dim3(DMODEL * DMODEL / 1024), 256, 0, stream>>>(Wv, wv16, DMODEL * DMODEL / 4);
  cvt_kernel<<<dim3(DMODEL * DMODEL / 1024), 256, 0, stream>>>(Wo, wo16, DMODEL * DMODEL / 4);
  cvt_kernel<<<dim3(DFFN * DMODEL / 1024), 256, 0, stream>>>(W1, w116, DFFN * DMODEL / 4);
  cvt_kernel<<<dim3(DMODEL * DFFN / 1024), 256, 0, stream>>>(W2, w216, DMODEL * DFFN / 4);

  dim3 gQKV(NTOK / 128, DMODEL / 128);
  gemm_bt<0><<<gQKV, 256, 0, stream>>>(fb16, wq16, NTOK, DMODEL, DMODEL, nullptr, nullptr, nullptr, q16);
  gemm_bt<0><<<gQKV, 256, 0, stream>>>(fb16, wk16, NTOK, DMODEL, DMODEL, nullptr, nullptr, nullptr, k16);
  gemm_bt<0><<<gQKV, 256, 0, stream>>>(fb16, wv16, NTOK, DMODEL, DMODEL, nullptr, nullptr, nullptr, v16);
  transpose_kernel<<<dim3(NTOK / 64, DMODEL / 64), 256, 0, stream>>>(v16, vt16);
  attn2_kernel<<<dim3(NTOK / 32 * NHEAD), 128, 0, stream>>>(q16, k16, vt16, coords, att16);
  gemm_bt<1><<<gQKV, 256, 0, stream>>>(att16, wo16, NTOK, DMODEL, DMODEL, bo, features, acc1, nullptr);
  ln_kernel<<<dim3(NTOK), 256, 0, stream>>>(acc1, ln1g, ln1b, xf, x16);
  gemm_bt<2><<<dim3(NTOK / 128, DFFN / 128), 256, 0, stream>>>(x16, w116, NTOK, DFFN, DMODEL, b1, nullptr, nullptr, h16);
  gemm_bt<3><<<gQKV, 256, 0, stream>>>(h16, w216, NTOK, DMODEL, DFFN, b2, xf, acc1, nullptr);
  ln_kernel<<<dim3(NTOK), 256, 0, stream>>>(acc1, ln2g, ln2b, outp, nullptr);
}

// Round 4
// 539.539 us; speedup vs baseline: 1.3354x; 1.1496x over previous
//
#include <hip/hip_runtime.h>
#include <cstdint>
#include <cstddef>

#define NTOK 4096
#define DMODEL 1024
#define NHEAD 8
#define DHEAD 128
#define DFFN 1536
#define LNEPS 1e-5f

typedef __bf16 bf16_t;
typedef __bf16 bf16x8 __attribute__((ext_vector_type(8)));
typedef __bf16 bf16x4 __attribute__((ext_vector_type(4)));
typedef float f32x4 __attribute__((ext_vector_type(4)));
typedef float f32x16 __attribute__((ext_vector_type(16)));

__device__ __forceinline__ void gload_lds16(const bf16_t* g, bf16_t* lds) {
  __builtin_amdgcn_global_load_lds(
      (const __attribute__((address_space(1))) unsigned int*)g,
      (__attribute__((address_space(3))) unsigned int*)lds, 16, 0, 0);
}

__device__ __forceinline__ unsigned pkbf(float lo, float hi) {
  unsigned a = (unsigned)__builtin_bit_cast(unsigned short, (bf16_t)lo);
  unsigned b = (unsigned)__builtin_bit_cast(unsigned short, (bf16_t)hi);
  return (b << 16) | a;
}

// ---------------- f32 -> bf16 convert ----------------
__global__ __launch_bounds__(256) void cvt_kernel(const float* __restrict__ in,
                                                  bf16_t* __restrict__ out, int n4) {
  int i = blockIdx.x * 256 + threadIdx.x;
  if (i < n4) {
    const float4 v = reinterpret_cast<const float4*>(in)[i];
    bf16x4 o = {(bf16_t)v.x, (bf16_t)v.y, (bf16_t)v.z, (bf16_t)v.w};
    reinterpret_cast<bf16x4*>(out)[i] = o;
  }
}

// ---------------- bf16 GEMM, C = A @ B^T (+ epilogue) ----------------
template<int EPI>
__global__ __launch_bounds__(256) void gemm_bt(
    const bf16_t* __restrict__ A, const bf16_t* __restrict__ B,
    int M, int Nn, int K,
    const float* __restrict__ bias, const float* __restrict__ resid,
    float* __restrict__ outF, bf16_t* __restrict__ outH)
{
  __shared__ bf16_t As[128 * 32];
  __shared__ bf16_t Bs[128 * 32];
  const int t = threadIdx.x;
  const int w = t >> 6, l = t & 63;
  const int lg = l >> 4, li = l & 15;
  const int m0 = blockIdx.x * 128, n0 = blockIdx.y * 128;
  const int wr = (w >> 1) * 64, wc = (w & 1) * 64;
  const f32x4 fz = {0.f, 0.f, 0.f, 0.f};
  f32x4 acc[4][4];
#pragma unroll
  for (int i = 0; i < 4; i++)
#pragma unroll
    for (int j = 0; j < 4; j++) acc[i][j] = fz;

  const bf16_t* Ag = A + (size_t)m0 * K;
  const bf16_t* Bg = B + (size_t)n0 * K;

  for (int kt = 0; kt < K; kt += 32) {
    if (kt) __syncthreads();
#pragma unroll
    for (int p = 0; p < 2; p++) {
      int c = p * 256 + w * 64 + l;
      gload_lds16(Ag + (size_t)(c >> 2) * K + kt + (c & 3) * 8,
                  As + (p * 256 + w * 64) * 8);
      gload_lds16(Bg + (size_t)(c >> 2) * K + kt + (c & 3) * 8,
                  Bs + (p * 256 + w * 64) * 8);
    }
    __syncthreads();
    bf16x8 af[4], bfr[4];
#pragma unroll
    for (int mi = 0; mi < 4; mi++)
      af[mi] = *reinterpret_cast<const bf16x8*>(&As[(wr + mi * 16 + li) * 32 + lg * 8]);
#pragma unroll
    for (int ni = 0; ni < 4; ni++)
      bfr[ni] = *reinterpret_cast<const bf16x8*>(&Bs[(wc + ni * 16 + li) * 32 + lg * 8]);
#pragma unroll
    for (int mi = 0; mi < 4; mi++)
#pragma unroll
      for (int ni = 0; ni < 4; ni++)
        acc[mi][ni] = __builtin_amdgcn_mfma_f32_16x16x32_bf16(af[mi], bfr[ni], acc[mi][ni], 0, 0, 0);
  }

#pragma unroll
  for (int mi = 0; mi < 4; mi++) {
#pragma unroll
    for (int ni = 0; ni < 4; ni++) {
      int gcol = n0 + wc + ni * 16 + li;
#pragma unroll
      for (int r = 0; r < 4; r++) {
        int grow = m0 + wr + mi * 16 + lg * 4 + r;
        float v = acc[mi][ni][r];
        if (EPI == 0) {
          outH[(size_t)grow * Nn + gcol] = (bf16_t)v;
        } else if (EPI == 1) {
          v += bias[gcol] + resid[(size_t)grow * Nn + gcol];
          outF[(size_t)grow * Nn + gcol] = v;
        } else if (EPI == 2) {
          v += bias[gcol];
          v = 0.5f * v * (1.f + erff(v * 0.70710678118654752f));
          outH[(size_t)grow * Nn + gcol] = (bf16_t)v;
        } else {
          v += bias[gcol] + resid[(size_t)grow * Nn + gcol];
          outF[(size_t)grow * Nn + gcol] = v;
        }
      }
    }
  }
}

// ---------------- bf16 transpose [NTOK,DMODEL] -> [DMODEL,NTOK] ----------------
__global__ __launch_bounds__(256) void transpose_kernel(const bf16_t* __restrict__ in,
                                                        bf16_t* __restrict__ out)
{
  __shared__ bf16_t tile[64][72];
  int t = threadIdx.x;
  int nb = blockIdx.x * 64, db = blockIdx.y * 64;
#pragma unroll
  for (int p = 0; p < 2; p++) {
    int c = p * 256 + t;
    int n = c >> 3, cb = c & 7;
    bf16x8 v = *reinterpret_cast<const bf16x8*>(in + (size_t)(nb + n) * DMODEL + db + cb * 8);
    *reinterpret_cast<bf16x8*>(&tile[n][cb * 8]) = v;
  }
  __syncthreads();
#pragma unroll
  for (int p = 0; p < 2; p++) {
    int c = p * 256 + t;
    int d = c >> 3, nc = (c & 7) * 8;
    bf16x8 vv;
#pragma unroll
    for (int j = 0; j < 8; j++) vv[j] = tile[nc + j][d];
    *reinterpret_cast<bf16x8*>(out + (size_t)(db + d) * NTOK + nb + nc) = vv;
  }
}

// ---------------- fused dual-softmax flash attention, v3 ----------------
// 128 threads = 2 waves; wave w owns kv-half w. NO LDS in the main loop:
// K-frags and V^T-frags are loaded directly global->VGPR (fragment layout
// row = lane&31, k = 8*(lane>>5)+j maps to contiguous 16B of row-major
// K / Vt). exp via exp2 with log2e folded into scales. Swapped QK^T
// (S^T, q=lane&31), shfl_xor(32) P->B-frag, PV as O^T = V^T * P^T.
__global__ __launch_bounds__(128, 2) void attn3_kernel(
    const bf16_t* __restrict__ Q, const bf16_t* __restrict__ K,
    const bf16_t* __restrict__ Vt, const int* __restrict__ coords,
    bf16_t* __restrict__ out)
{
  __shared__ float cmbA[128 * 32];
  __shared__ float oT[128 * 33];
  __shared__ float mlS[4][32];

  const int t = threadIdx.x;
  const int w = t >> 6;
  const int l = t & 63;
  const int q5 = l & 31;
  const int hi = l >> 5;
  const int h = blockIdx.x & 7;
  const int q0 = (blockIdx.x >> 3) * 32;
  const float LOG2E = 1.44269504088896f;
  const float isq = 0.08838834764831845f;   // 1/sqrt(128)
  const float itau = 1.6666666666666667f;   // 1/0.6
  const float hs = 1.0f / (float)(2 << h);
  const float ap = isq * LOG2E;             // S scale, pos (log2 units)
  const float an = -isq * itau * LOG2E;     // S scale, neg
  const float bpp = hs * LOG2E;             // bias scale, pos
  const float bnp = hs * itau * LOG2E;      // bias scale, neg

  // preload Q fragments (B-operand: col q = lane&31, k = d = 16c + 8hi + j)
  bf16x8 qf[8];
  {
    const bf16_t* qrow = Q + (size_t)(q0 + q5) * DMODEL + h * DHEAD;
#pragma unroll
    for (int c = 0; c < 8; c++)
      qf[c] = *reinterpret_cast<const bf16x8*>(qrow + c * 16 + hi * 8);
  }
  const float qx = (float)coords[(q0 + q5) * 2];
  const float qy = (float)coords[(q0 + q5) * 2 + 1];

  f32x16 accp[4], accn[4];
#pragma unroll
  for (int f = 0; f < 4; f++) {
#pragma unroll
    for (int r = 0; r < 16; r++) { accp[f][r] = 0.f; accn[f][r] = 0.f; }
  }
  float mp = -3e38f, mn = -3e38f, lp = 0.f, lN = 0.f;

  // per-lane fixed row bases
  const bf16_t* krow = K + (size_t)(w * 2048 + q5) * DMODEL + h * DHEAD + hi * 8;
  const bf16_t* vrow0 = Vt + (size_t)(h * DHEAD + q5) * NTOK + w * 2048 + hi * 8;

  for (int it = 0; it < 64; it++) {
    const int kv0 = w * 2048 + it * 32;

    // ---- issue K-frag loads (direct global; row kv0+q5) ----
    bf16x8 kf[8];
    {
      const bf16_t* kp = krow + (size_t)it * 32 * DMODEL;
#pragma unroll
      for (int c = 0; c < 8; c++)
        kf[c] = *reinterpret_cast<const bf16x8*>(kp + c * 16);
    }

    // ---- bias sqrt while K loads are in flight ----
    float br[16];
#pragma unroll
    for (int r = 0; r < 16; r++) {
      int kvr = kv0 + (r & 3) + 8 * (r >> 2) + 4 * hi;
      float kx = (float)coords[kvr * 2];
      float ky = (float)coords[kvr * 2 + 1];
      float dx = qx - kx, dy = qy - ky;
      br[r] = sqrtf(dx * dx + dy * dy);
    }

    // ---- S^T = K * Q^T (32 kv x 32 q) ----
    f32x16 sacc;
#pragma unroll
    for (int r = 0; r < 16; r++) sacc[r] = 0.f;
#pragma unroll
    for (int c = 0; c < 8; c++)
      sacc = __builtin_amdgcn_mfma_f32_32x32x16_bf16(kf[c], qf[c], sacc, 0, 0, 0);

    // ---- issue V-frag loads (used after softmax; latency hidden) ----
    bf16x8 vf[8];
#pragma unroll
    for (int ks = 0; ks < 2; ks++)
#pragma unroll
      for (int f = 0; f < 4; f++)
        vf[ks * 4 + f] = *reinterpret_cast<const bf16x8*>(
            vrow0 + (size_t)(32 * f) * NTOK + it * 32 + ks * 16);

    // ---- dual online softmax in log2 domain ----
    float p16[16], n16[16];
    float tp = -3e38f, tn = -3e38f;
#pragma unroll
    for (int r = 0; r < 16; r++) {
      float e1 = sacc[r] * ap - br[r] * bpp;
      float e2 = sacc[r] * an - br[r] * bnp;
      p16[r] = e1; n16[r] = e2;
      tp = fmaxf(tp, e1); tn = fmaxf(tn, e2);
    }
    tp = fmaxf(tp, __shfl_xor(tp, 32, 64));
    tn = fmaxf(tn, __shfl_xor(tn, 32, 64));

    if (__any((tp > mp + 8.f) || (tn > mn + 8.f))) {
      float mpn = fmaxf(mp, tp), mnn = fmaxf(mn, tn);
      float cp = exp2f(mp - mpn), cn = exp2f(mn - mnn);
      mp = mpn; mn = mnn; lp *= cp; lN *= cn;
#pragma unroll
      for (int f = 0; f < 4; f++) {
#pragma unroll
        for (int r = 0; r < 16; r++) { accp[f][r] *= cp; accn[f][r] *= cn; }
      }
    }
    float rp = 0.f, rn = 0.f;
#pragma unroll
    for (int r = 0; r < 16; r++) {
      p16[r] = exp2f(p16[r] - mp); rp += p16[r];
      n16[r] = exp2f(n16[r] - mn); rn += n16[r];
    }
    rp += __shfl_xor(rp, 32, 64);
    rn += __shfl_xor(rn, 32, 64);
    lp += rp; lN += rn;

    // ---- pack P^T to bf16 B-frags, redistribute via shfl_xor(32) ----
    unsigned pw[2][4], nw[2][4];
#pragma unroll
    for (int ks = 0; ks < 2; ks++) {
#pragma unroll
      for (int u = 0; u < 2; u++) {
        unsigned A = pkbf(p16[8 * ks + 2 * u], p16[8 * ks + 2 * u + 1]);
        unsigned B = pkbf(p16[8 * ks + 4 + 2 * u], p16[8 * ks + 4 + 2 * u + 1]);
        unsigned Ax = __shfl_xor(A, 32, 64);
        unsigned Bx = __shfl_xor(B, 32, 64);
        pw[ks][u] = hi ? Bx : A;
        pw[ks][2 + u] = hi ? B : Ax;
        unsigned C = pkbf(n16[8 * ks + 2 * u], n16[8 * ks + 2 * u + 1]);
        unsigned D = pkbf(n16[8 * ks + 4 + 2 * u], n16[8 * ks + 4 + 2 * u + 1]);
        unsigned Cx = __shfl_xor(C, 32, 64);
        unsigned Dx = __shfl_xor(D, 32, 64);
        nw[ks][u] = hi ? Dx : C;
        nw[ks][2 + u] = hi ? D : Cx;
      }
    }

    // ---- PV: O^T += V^T * P^T ----
#pragma unroll
    for (int ks = 0; ks < 2; ks++) {
      union { unsigned u[4]; bf16x8 v; } pb, nb;
#pragma unroll
      for (int j = 0; j < 4; j++) { pb.u[j] = pw[ks][j]; nb.u[j] = nw[ks][j]; }
#pragma unroll
      for (int f = 0; f < 4; f++) {
        accp[f] = __builtin_amdgcn_mfma_f32_32x32x16_bf16(vf[ks * 4 + f], pb.v, accp[f], 0, 0, 0);
        accn[f] = __builtin_amdgcn_mfma_f32_32x32x16_bf16(vf[ks * 4 + f], nb.v, accn[f], 0, 0, 0);
      }
    }
  }

  // ---- cross-wave combine (kv half 0 + half 1) ----
  __syncthreads();
  if (w == 1) {
    if (hi == 0) { mlS[0][q5] = mp; mlS[1][q5] = lp; mlS[2][q5] = mn; mlS[3][q5] = lN; }
#pragma unroll
    for (int f = 0; f < 4; f++)
#pragma unroll
      for (int r = 0; r < 16; r++)
        cmbA[(32 * f + (r & 3) + 8 * (r >> 2) + 4 * hi) * 32 + q5] = accp[f][r];
  }
  __syncthreads();
  float mp1 = mlS[0][q5], lp1 = mlS[1][q5], mn1 = mlS[2][q5], ln1 = mlS[3][q5];
  if (w == 0) {
    float mpc = fmaxf(mp, mp1);
    float e0 = exp2f(mp - mpc), e1 = exp2f(mp1 - mpc);
    lp = lp * e0 + lp1 * e1;
#pragma unroll
    for (int f = 0; f < 4; f++)
#pragma unroll
      for (int r = 0; r < 16; r++)
        accp[f][r] = accp[f][r] * e0 +
                     cmbA[(32 * f + (r & 3) + 8 * (r >> 2) + 4 * hi) * 32 + q5] * e1;
  }
  __syncthreads();
  if (w == 1) {
#pragma unroll
    for (int f = 0; f < 4; f++)
#pragma unroll
      for (int r = 0; r < 16; r++)
        cmbA[(32 * f + (r & 3) + 8 * (r >> 2) + 4 * hi) * 32 + q5] = accn[f][r];
  }
  __syncthreads();
  if (w == 0) {
    float mnc = fmaxf(mn, mn1);
    float e0 = exp2f(mn - mnc), e1 = exp2f(mn1 - mnc);
    lN = lN * e0 + ln1 * e1;
    float ip = 1.f / lp, inn = 1.5f / lN;
#pragma unroll
    for (int f = 0; f < 4; f++)
#pragma unroll
      for (int r = 0; r < 16; r++) {
        float an2 = accn[f][r] * e0 +
                    cmbA[(32 * f + (r & 3) + 8 * (r >> 2) + 4 * hi) * 32 + q5] * e1;
        oT[(32 * f + (r & 3) + 8 * (r >> 2) + 4 * hi) * 33 + q5] =
            accp[f][r] * ip - an2 * inn;
      }
  }
  __syncthreads();

  // ---- transpose store: thread t -> q = t>>2, d-quarter = (t&3)*32 ----
  {
    int q = t >> 2, dq = (t & 3) * 32;
#pragma unroll
    for (int j = 0; j < 4; j++) {
      bf16x8 ov;
#pragma unroll
      for (int e = 0; e < 8; e++) ov[e] = (bf16_t)oT[(dq + j * 8 + e) * 33 + q];
      *reinterpret_cast<bf16x8*>(out + (size_t)(q0 + q) * DMODEL + h * DHEAD + dq + j * 8) = ov;
    }
  }
}

// ---------------- row LayerNorm (D=1024) ----------------
__global__ __launch_bounds__(256) void ln_kernel(
    const float* __restrict__ in, const float* __restrict__ g, const float* __restrict__ b,
    float* __restrict__ outF, bf16_t* __restrict__ outH)
{
  int row = blockIdx.x, t = threadIdx.x;
  const float4 v = reinterpret_cast<const float4*>(in + (size_t)row * DMODEL)[t];
  float s = v.x + v.y + v.z + v.w;
  float ss = v.x * v.x + v.y * v.y + v.z * v.z + v.w * v.w;
#pragma unroll
  for (int m = 32; m >= 1; m >>= 1) {
    s += __shfl_xor(s, m, 64);
    ss += __shfl_xor(ss, m, 64);
  }
  __shared__ float red[8];
  int w = t >> 6, l = t & 63;
  if (l == 0) { red[w] = s; red[4 + w] = ss; }
  __syncthreads();
  s = red[0] + red[1] + red[2] + red[3];
  ss = red[4] + red[5] + red[6] + red[7];
  float mu = s * (1.f / DMODEL);
  float var = ss * (1.f / DMODEL) - mu * mu;
  float rs = rsqrtf(var + LNEPS);
  const float4 gv = reinterpret_cast<const float4*>(g)[t];
  const float4 bv = reinterpret_cast<const float4*>(b)[t];
  float y0 = (v.x - mu) * rs * gv.x + bv.x;
  float y1 = (v.y - mu) * rs * gv.y + bv.y;
  float y2 = (v.z - mu) * rs * gv.z + bv.z;
  float y3 = (v.w - mu) * rs * gv.w + bv.w;
  if (outF) {
    float4 o; o.x = y0; o.y = y1; o.z = y2; o.w = y3;
    reinterpret_cast<float4*>(outF + (size_t)row * DMODEL)[t] = o;
  }
  if (outH) {
    bf16x4 o = {(bf16_t)y0, (bf16_t)y1, (bf16_t)y2, (bf16_t)y3};
    reinterpret_cast<bf16x4*>(outH + (size_t)row * DMODEL)[t] = o;
  }
}

extern "C" void kernel_launch(void* const* d_in, const int* in_sizes, int n_in,
                              void* d_out, int out_size, void* d_ws, size_t ws_size,
                              hipStream_t stream) {
  (void)in_sizes; (void)n_in; (void)out_size; (void)ws_size;
  const float* features = (const float*)d_in[0];
  const int* coords = (const int*)d_in[1];
  const float* Wq = (const float*)d_in[2];
  const float* Wk = (const float*)d_in[3];
  const float* Wv = (const float*)d_in[4];
  const float* Wo = (const float*)d_in[5];
  const float* bo = (const float*)d_in[6];
  const float* ln1g = (const float*)d_in[7];
  const float* ln1b = (const float*)d_in[8];
  const float* W1 = (const float*)d_in[9];
  const float* b1 = (const float*)d_in[10];
  const float* W2 = (const float*)d_in[11];
  const float* b2 = (const float*)d_in[12];
  const float* ln2g = (const float*)d_in[13];
  const float* ln2b = (const float*)d_in[14];
  float* outp = (float*)d_out;

  char* ws = (char*)d_ws;
  size_t off = 0;
  auto alloc = [&](size_t bytes) -> void* {
    void* p = ws + off;
    off += (bytes + 255) & ~((size_t)255);
    return p;
  };
  bf16_t* fb16 = (bf16_t*)alloc((size_t)NTOK * DMODEL * 2);
  bf16_t* wq16 = (bf16_t*)alloc((size_t)DMODEL * DMODEL * 2);
  bf16_t* wk16 = (bf16_t*)alloc((size_t)DMODEL * DMODEL * 2);
  bf16_t* wv16 = (bf16_t*)alloc((size_t)DMODEL * DMODEL * 2);
  bf16_t* wo16 = (bf16_t*)alloc((size_t)DMODEL * DMODEL * 2);
  bf16_t* w116 = (bf16_t*)alloc((size_t)DFFN * DMODEL * 2);
  bf16_t* w216 = (bf16_t*)alloc((size_t)DMODEL * DFFN * 2);
  bf16_t* q16 = (bf16_t*)alloc((size_t)NTOK * DMODEL * 2);
  bf16_t* k16 = (bf16_t*)alloc((size_t)NTOK * DMODEL * 2);
  bf16_t* v16 = (bf16_t*)alloc((size_t)NTOK * DMODEL * 2);
  bf16_t* vt16 = (bf16_t*)alloc((size_t)NTOK * DMODEL * 2);
  float* acc1 = (float*)alloc((size_t)NTOK * DMODEL * 4);
  float* xf = (float*)alloc((size_t)NTOK * DMODEL * 4);
  bf16_t* x16 = (bf16_t*)alloc((size_t)NTOK * DMODEL * 2);
  bf16_t* h16 = (bf16_t*)alloc((size_t)NTOK * DFFN * 2);
  bf16_t* att16 = fb16;

  cvt_kernel<<<dim3(NTOK * DMODEL / 1024), 256, 0, stream>>>(features, fb16, NTOK * DMODEL / 4);
  cvt_kernel<<<dim3(DMODEL * DMODEL / 1024), 256, 0, stream>>>(Wq, wq16, DMODEL * DMODEL / 4);
  cvt_kernel<<<dim3(DMODEL * DMODEL / 1024), 256, 0, stream>>>(Wk, wk16, DMODEL * DMODEL / 4);
  cvt_kernel<<<dim3(DMODEL * DMODEL / 1024), 256, 0, stream>>>(Wv, wv16, DMODEL * DMODEL / 4);
  cvt_kernel<<<dim3(DMODEL * DMODEL / 1024), 256, 0, stream>>>(Wo, wo16, DMODEL * DMODEL / 4);
  cvt_kernel<<<dim3(DFFN * DMODEL / 1024), 256, 0, stream>>>(W1, w116, DFFN * DMODEL / 4);
  cvt_kernel<<<dim3(DMODEL * DFFN / 1024), 256, 0, stream>>>(W2, w216, DMODEL * DFFN / 4);

  dim3 gQKV(NTOK / 128, DMODEL / 128);
  gemm_bt<0><<<gQKV, 256, 0, stream>>>(fb16, wq16, NTOK, DMODEL, DMODEL, nullptr, nullptr, nullptr, q16);
  gemm_bt<0><<<gQKV, 256, 0, stream>>>(fb16, wk16, NTOK, DMODEL, DMODEL, nullptr, nullptr, nullptr, k16);
  gemm_bt<0><<<gQKV, 256, 0, stream>>>(fb16, wv16, NTOK, DMODEL, DMODEL, nullptr, nullptr, nullptr, v16);
  transpose_kernel<<<dim3(NTOK / 64, DMODEL / 64), 256, 0, stream>>>(v16, vt16);
  attn3_kernel<<<dim3(NTOK / 32 * NHEAD), 128, 0, stream>>>(q16, k16, vt16, coords, att16);
  gemm_bt<1><<<gQKV, 256, 0, stream>>>(att16, wo16, NTOK, DMODEL, DMODEL, bo, features, acc1, nullptr);
  ln_kernel<<<dim3(NTOK), 256, 0, stream>>>(acc1, ln1g, ln1b, xf, x16);
  gemm_bt<2><<<dim3(NTOK / 128, DFFN / 128), 256, 0, stream>>>(x16, w116, NTOK, DFFN, DMODEL, b1, nullptr, nullptr, h16);
  gemm_bt<3><<<gQKV, 256, 0, stream>>>(h16, w216, NTOK, DMODEL, DFFN, b2, xf, acc1, nullptr);
  ln_kernel<<<dim3(NTOK), 256, 0, stream>>>(acc1, ln2g, ln2b, outp, nullptr);
}